// Round 1
// baseline (843.737 us; speedup 1.0000x reference)
//
#include <hip/hip_runtime.h>
#include <math.h>

#define BATCH 16
#define CCH 256
#define HW 1024
#define NH 8
#define HD 32
#define SCALE 0.17677669529663687f  // 1/sqrt(32)

// ---------------------------------------------------------------------------
// Kernel 1: qkv = w_qkv(768x256) @ x_b(256x1024); write Q/K/V as [b][head][p][d]
// ---------------------------------------------------------------------------
__global__ __launch_bounds__(256) void qkv_gemm(const float* __restrict__ x,
                                                const float* __restrict__ w,
                                                float* __restrict__ Q,
                                                float* __restrict__ Kp,
                                                float* __restrict__ Vp) {
  __shared__ float Wt[64][68];
  __shared__ float Xt[64][68];
  const int t = threadIdx.x;
  const int o0 = blockIdx.x * 64;   // 0..11
  const int p0 = blockIdx.y * 64;   // 0..15
  const int b  = blockIdx.z;
  const int tx = t & 15, ty = t >> 4;
  float acc[4][4] = {};
  for (int c0 = 0; c0 < CCH; c0 += 64) {
#pragma unroll
    for (int k = 0; k < 4; ++k) {
      int fidx = t + k * 256;            // 1024 float4 per tile
      int r = fidx >> 4, c4 = fidx & 15;
      *(float4*)&Wt[r][c4 * 4] =
          *(const float4*)(w + (size_t)(o0 + r) * CCH + c0 + c4 * 4);
      *(float4*)&Xt[r][c4 * 4] =
          *(const float4*)(x + (size_t)b * (CCH * HW) + (size_t)(c0 + r) * HW + p0 + c4 * 4);
    }
    __syncthreads();
#pragma unroll
    for (int cc4 = 0; cc4 < 16; ++cc4) {
      float xs[4][4];
#pragma unroll
      for (int q = 0; q < 4; ++q) {
        float4 v = *(const float4*)&Xt[cc4 * 4 + q][tx * 4];
        xs[q][0] = v.x; xs[q][1] = v.y; xs[q][2] = v.z; xs[q][3] = v.w;
      }
#pragma unroll
      for (int i = 0; i < 4; ++i) {
        float4 wv = *(const float4*)&Wt[ty * 4 + i][cc4 * 4];
#pragma unroll
        for (int j = 0; j < 4; ++j)
          acc[i][j] += wv.x * xs[0][j] + wv.y * xs[1][j] + wv.z * xs[2][j] + wv.w * xs[3][j];
      }
    }
    __syncthreads();
  }
  // scatter to Q/K/V [b][head][p][d]
#pragma unroll
  for (int i = 0; i < 4; ++i) {
    int o = o0 + ty * 4 + i;            // 0..767
    int three = o >> 8;
    int head = (o >> 5) & 7;
    int d = o & 31;
    float* dst = (three == 0) ? Q : (three == 1) ? Kp : Vp;
    size_t base = (size_t)(b * NH + head) * (HW * HD);
#pragma unroll
    for (int j = 0; j < 4; ++j) {
      int p = p0 + tx * 4 + j;
      dst[base + (size_t)p * HD + d] = acc[i][j];
    }
  }
}

// ---------------------------------------------------------------------------
// Kernel 2: attention, flash-lite (no max subtraction; single pass, online
// sum-of-exp). Block = 256 thr handles one (b*head, 64-query tile).
// Thread: 2 query rows x 8 keys per 64-key tile; float4 LDS reads.
// Output A in [b][c][p] layout (c = head*32+d).
// ---------------------------------------------------------------------------
__global__ __launch_bounds__(256) void attn_kernel(const float* __restrict__ Q,
                                                   const float* __restrict__ K,
                                                   const float* __restrict__ V,
                                                   float* __restrict__ A) {
  __shared__ float Qs[64][36];
  __shared__ float Ks[64][36];
  __shared__ float Vs[64][36];
  const int t = threadIdx.x;
  const int i0 = blockIdx.x * 64;
  const int bh = blockIdx.y;
  const float* Qb = Q + (size_t)bh * (HW * HD);
  const float* Kb = K + (size_t)bh * (HW * HD);
  const float* Vb = V + (size_t)bh * (HW * HD);

  {
    const float4* src = (const float4*)(Qb + (size_t)i0 * HD);
#pragma unroll
    for (int k = 0; k < 2; ++k) {
      int fidx = t + k * 256;           // 512 float4
      int r = fidx >> 3, c4 = fidx & 7;
      *(float4*)&Qs[r][c4 * 4] = src[fidx];
    }
  }
  __syncthreads();

  const int g = t >> 3;   // row group 0..31 (rows 2g, 2g+1)
  const int s = t & 7;    // sub-lane: keys j = jj*8 + s
  float4 q4[2][8];
  float4 o4[2][8];
  float l_acc[2] = {0.f, 0.f};
#pragma unroll
  for (int ii = 0; ii < 2; ++ii)
#pragma unroll
    for (int d4 = 0; d4 < 8; ++d4) {
      float4 v = *(const float4*)&Qs[g * 2 + ii][d4 * 4];
      v.x *= SCALE; v.y *= SCALE; v.z *= SCALE; v.w *= SCALE;
      q4[ii][d4] = v;
      o4[ii][d4] = make_float4(0.f, 0.f, 0.f, 0.f);
    }

  for (int jt = 0; jt < 16; ++jt) {
    __syncthreads();
    {
      const float4* ksrc = (const float4*)(Kb + (size_t)jt * 64 * HD);
      const float4* vsrc = (const float4*)(Vb + (size_t)jt * 64 * HD);
#pragma unroll
      for (int k = 0; k < 2; ++k) {
        int fidx = t + k * 256;
        int r = fidx >> 3, c4 = fidx & 7;
        *(float4*)&Ks[r][c4 * 4] = ksrc[fidx];
        *(float4*)&Vs[r][c4 * 4] = vsrc[fidx];
      }
    }
    __syncthreads();
#pragma unroll
    for (int jj = 0; jj < 8; ++jj) {
      int j = jj * 8 + s;
      float sc0 = 0.f, sc1 = 0.f;
#pragma unroll
      for (int d4 = 0; d4 < 8; ++d4) {
        float4 kv = *(const float4*)&Ks[j][d4 * 4];
        sc0 += q4[0][d4].x * kv.x + q4[0][d4].y * kv.y + q4[0][d4].z * kv.z + q4[0][d4].w * kv.w;
        sc1 += q4[1][d4].x * kv.x + q4[1][d4].y * kv.y + q4[1][d4].z * kv.z + q4[1][d4].w * kv.w;
      }
      float e0 = __expf(sc0);
      float e1 = __expf(sc1);
      l_acc[0] += e0;
      l_acc[1] += e1;
#pragma unroll
      for (int d4 = 0; d4 < 8; ++d4) {
        float4 vv = *(const float4*)&Vs[j][d4 * 4];
        o4[0][d4].x += e0 * vv.x; o4[0][d4].y += e0 * vv.y;
        o4[0][d4].z += e0 * vv.z; o4[0][d4].w += e0 * vv.w;
        o4[1][d4].x += e1 * vv.x; o4[1][d4].y += e1 * vv.y;
        o4[1][d4].z += e1 * vv.z; o4[1][d4].w += e1 * vv.w;
      }
    }
  }
  // reduce across the 8 s-lanes of each row group (consecutive lanes, same wave)
#pragma unroll
  for (int ii = 0; ii < 2; ++ii) {
    l_acc[ii] += __shfl_xor(l_acc[ii], 1);
    l_acc[ii] += __shfl_xor(l_acc[ii], 2);
    l_acc[ii] += __shfl_xor(l_acc[ii], 4);
  }
#pragma unroll
  for (int ii = 0; ii < 2; ++ii)
#pragma unroll
    for (int d4 = 0; d4 < 8; ++d4) {
      float4 v = o4[ii][d4];
#pragma unroll
      for (int m = 1; m < 8; m <<= 1) {
        v.x += __shfl_xor(v.x, m);
        v.y += __shfl_xor(v.y, m);
        v.z += __shfl_xor(v.z, m);
        v.w += __shfl_xor(v.w, m);
      }
      o4[ii][d4] = v;
    }
  // lane s writes d = s*4 .. s*4+3 (avoid dynamic register indexing via select chain)
  float* dst = A + (size_t)bh * (HD * HW);
#pragma unroll
  for (int ii = 0; ii < 2; ++ii) {
    float inv = 1.f / l_acc[ii];
    int p = i0 + g * 2 + ii;
    float4 v = o4[ii][0];
#pragma unroll
    for (int d4 = 1; d4 < 8; ++d4)
      if (d4 == s) v = o4[ii][d4];
    dst[(size_t)(s * 4 + 0) * HW + p] = v.x * inv;
    dst[(size_t)(s * 4 + 1) * HW + p] = v.y * inv;
    dst[(size_t)(s * 4 + 2) * HW + p] = v.z * inv;
    dst[(size_t)(s * 4 + 3) * HW + p] = v.w * inv;
  }
}

// ---------------------------------------------------------------------------
// Kernel 3: proj = w_proj(256x256) @ A_b(256x1024) -> P [b][c][p]
// ---------------------------------------------------------------------------
__global__ __launch_bounds__(256) void proj_gemm(const float* __restrict__ Ain,
                                                 const float* __restrict__ w,
                                                 float* __restrict__ P) {
  __shared__ float Wt[64][68];
  __shared__ float Xt[64][68];
  const int t = threadIdx.x;
  const int o0 = blockIdx.x * 64;   // 0..3
  const int p0 = blockIdx.y * 64;   // 0..15
  const int b  = blockIdx.z;
  const int tx = t & 15, ty = t >> 4;
  float acc[4][4] = {};
  for (int c0 = 0; c0 < CCH; c0 += 64) {
#pragma unroll
    for (int k = 0; k < 4; ++k) {
      int fidx = t + k * 256;
      int r = fidx >> 4, c4 = fidx & 15;
      *(float4*)&Wt[r][c4 * 4] =
          *(const float4*)(w + (size_t)(o0 + r) * CCH + c0 + c4 * 4);
      *(float4*)&Xt[r][c4 * 4] =
          *(const float4*)(Ain + (size_t)b * (CCH * HW) + (size_t)(c0 + r) * HW + p0 + c4 * 4);
    }
    __syncthreads();
#pragma unroll
    for (int cc4 = 0; cc4 < 16; ++cc4) {
      float xs[4][4];
#pragma unroll
      for (int q = 0; q < 4; ++q) {
        float4 v = *(const float4*)&Xt[cc4 * 4 + q][tx * 4];
        xs[q][0] = v.x; xs[q][1] = v.y; xs[q][2] = v.z; xs[q][3] = v.w;
      }
#pragma unroll
      for (int i = 0; i < 4; ++i) {
        float4 wv = *(const float4*)&Wt[ty * 4 + i][cc4 * 4];
#pragma unroll
        for (int j = 0; j < 4; ++j)
          acc[i][j] += wv.x * xs[0][j] + wv.y * xs[1][j] + wv.z * xs[2][j] + wv.w * xs[3][j];
      }
    }
    __syncthreads();
  }
#pragma unroll
  for (int i = 0; i < 4; ++i) {
    int o = o0 + ty * 4 + i;
    float4 v = make_float4(acc[i][0], acc[i][1], acc[i][2], acc[i][3]);
    *(float4*)&P[(size_t)b * (CCH * HW) + (size_t)o * HW + p0 + tx * 4] = v;
  }
}

// ---------------------------------------------------------------------------
// Kernel 4: GroupNorm stats per (b,g): contiguous 32768-float segment of P
// ---------------------------------------------------------------------------
__global__ __launch_bounds__(256) void gn_stats(const float* __restrict__ P,
                                                float* __restrict__ stats) {
  __shared__ float r1[256], r2[256];
  const int t = threadIdx.x;
  const int bg = blockIdx.x;  // 0..127
  const float4* Pg = (const float4*)(P + (size_t)bg * 32768);
  float s1 = 0.f, s2 = 0.f;
  for (int idx = t; idx < 8192; idx += 256) {
    float4 v = Pg[idx];
    s1 += v.x + v.y + v.z + v.w;
    s2 += v.x * v.x + v.y * v.y + v.z * v.z + v.w * v.w;
  }
  r1[t] = s1; r2[t] = s2;
  __syncthreads();
  for (int off = 128; off > 0; off >>= 1) {
    if (t < off) { r1[t] += r1[t + off]; r2[t] += r2[t + off]; }
    __syncthreads();
  }
  if (t == 0) {
    float mean = r1[0] * (1.f / 32768.f);
    float var = r2[0] * (1.f / 32768.f) - mean * mean;
    stats[bg * 2] = mean;
    stats[bg * 2 + 1] = rsqrtf(var + 1e-5f);
  }
}

// ---------------------------------------------------------------------------
// Kernel 5: out = (P - mean)*inv*gamma + beta + x
// ---------------------------------------------------------------------------
__global__ __launch_bounds__(256) void gn_apply(const float* __restrict__ P,
                                                const float* __restrict__ x,
                                                const float* __restrict__ gamma,
                                                const float* __restrict__ beta,
                                                const float* __restrict__ stats,
                                                float* __restrict__ out) {
  int i4 = blockIdx.x * 256 + threadIdx.x;   // 1048576 float4s
  int c = (i4 >> 8) & 255;
  int bg = i4 >> 13;
  float mean = stats[bg * 2];
  float inv = stats[bg * 2 + 1];
  float ga = gamma[c] * inv;
  float be = beta[c] - mean * ga;
  float4 p = ((const float4*)P)[i4];
  float4 xr = ((const float4*)x)[i4];
  float4 o;
  o.x = p.x * ga + be + xr.x;
  o.y = p.y * ga + be + xr.y;
  o.z = p.z * ga + be + xr.z;
  o.w = p.w * ga + be + xr.w;
  ((float4*)out)[i4] = o;
}

// ---------------------------------------------------------------------------
extern "C" void kernel_launch(void* const* d_in, const int* in_sizes, int n_in,
                              void* d_out, int out_size, void* d_ws, size_t ws_size,
                              hipStream_t stream) {
  const float* x      = (const float*)d_in[0];
  const float* w_qkv  = (const float*)d_in[1];
  const float* w_proj = (const float*)d_in[2];
  const float* gamma  = (const float*)d_in[3];
  const float* beta   = (const float*)d_in[4];
  float* out = (float*)d_out;

  float* ws = (float*)d_ws;
  const size_t SZ = (size_t)BATCH * CCH * HW;  // 4,194,304 floats
  float* Q = ws;
  float* K = Q + SZ;
  float* V = K + SZ;
  float* A = V + SZ;
  float* P = A + SZ;
  float* stats = P + SZ;   // 256 floats

  qkv_gemm<<<dim3(12, 16, BATCH), 256, 0, stream>>>(x, w_qkv, Q, K, V);
  attn_kernel<<<dim3(16, BATCH * NH), 256, 0, stream>>>(Q, K, V, A);
  proj_gemm<<<dim3(4, 16, BATCH), 256, 0, stream>>>(A, w_proj, P);
  gn_stats<<<128, 256, 0, stream>>>(P, stats);
  gn_apply<<<4096, 256, 0, stream>>>(P, x, gamma, beta, stats, out);
}

// Round 2
// 451.287 us; speedup vs baseline: 1.8696x; 1.8696x over previous
//
#include <hip/hip_runtime.h>
#include <hip/hip_bf16.h>
#include <math.h>

#define BATCH 16
#define CCH 256
#define HW 1024
#define NH 8
#define HD 32
#define SCALE 0.17677669529663687f  // 1/sqrt(32)

typedef __attribute__((ext_vector_type(8))) short bf16x8;  // 8 bf16 = 4 VGPRs
typedef __attribute__((ext_vector_type(4))) float f32x4;

// ---------------------------------------------------------------------------
// Kernel 1: qkv = w_qkv(768x256) @ x_b(256x1024)
// Writes bf16: Q [bh][p][d] (pre-scaled by 1/sqrt(hd)), K [bh][p][d], Vt [bh][d][p]
// ---------------------------------------------------------------------------
__global__ __launch_bounds__(256) void qkv_gemm(const float* __restrict__ x,
                                                const float* __restrict__ w,
                                                __hip_bfloat16* __restrict__ Qb,
                                                __hip_bfloat16* __restrict__ Kb,
                                                __hip_bfloat16* __restrict__ Vtb) {
  __shared__ float Wt[64][68];
  __shared__ float Xt[64][68];
  const int t = threadIdx.x;
  const int o0 = blockIdx.x * 64;   // 0..11
  const int p0 = blockIdx.y * 64;   // 0..15
  const int b  = blockIdx.z;
  const int tx = t & 15, ty = t >> 4;
  float acc[4][4] = {};
  for (int c0 = 0; c0 < CCH; c0 += 64) {
#pragma unroll
    for (int k = 0; k < 4; ++k) {
      int fidx = t + k * 256;            // 1024 float4 per tile
      int r = fidx >> 4, c4 = fidx & 15;
      *(float4*)&Wt[r][c4 * 4] =
          *(const float4*)(w + (size_t)(o0 + r) * CCH + c0 + c4 * 4);
      *(float4*)&Xt[r][c4 * 4] =
          *(const float4*)(x + (size_t)b * (CCH * HW) + (size_t)(c0 + r) * HW + p0 + c4 * 4);
    }
    __syncthreads();
#pragma unroll
    for (int cc4 = 0; cc4 < 16; ++cc4) {
      float xs[4][4];
#pragma unroll
      for (int q = 0; q < 4; ++q) {
        float4 v = *(const float4*)&Xt[cc4 * 4 + q][tx * 4];
        xs[q][0] = v.x; xs[q][1] = v.y; xs[q][2] = v.z; xs[q][3] = v.w;
      }
#pragma unroll
      for (int i = 0; i < 4; ++i) {
        float4 wv = *(const float4*)&Wt[ty * 4 + i][cc4 * 4];
#pragma unroll
        for (int j = 0; j < 4; ++j)
          acc[i][j] += wv.x * xs[0][j] + wv.y * xs[1][j] + wv.z * xs[2][j] + wv.w * xs[3][j];
      }
    }
    __syncthreads();
  }
  // scatter to bf16 Q/K (scaled Q) [bh][p][d]; Vt transposed [bh][d][p]
#pragma unroll
  for (int i = 0; i < 4; ++i) {
    int o = o0 + ty * 4 + i;            // 0..767
    int three = o >> 8;
    int head = (o >> 5) & 7;
    int d = o & 31;
    size_t base = (size_t)(b * NH + head) * (HW * HD);
    if (three == 0) {
#pragma unroll
      for (int j = 0; j < 4; ++j) {
        int p = p0 + tx * 4 + j;
        Qb[base + (size_t)p * HD + d] = __float2bfloat16(acc[i][j] * SCALE);
      }
    } else if (three == 1) {
#pragma unroll
      for (int j = 0; j < 4; ++j) {
        int p = p0 + tx * 4 + j;
        Kb[base + (size_t)p * HD + d] = __float2bfloat16(acc[i][j]);
      }
    } else {
      __hip_bfloat16 tmp[4];
#pragma unroll
      for (int j = 0; j < 4; ++j) tmp[j] = __float2bfloat16(acc[i][j]);
      *(ushort4*)(&Vtb[base + (size_t)d * HW + p0 + tx * 4]) = *(const ushort4*)tmp;
    }
  }
}

// ---------------------------------------------------------------------------
// Kernel 2: MFMA flash attention. 1 wave = 16 queries x all keys.
// Per 64-key tile: 4 QK mfma(16x16x32) -> exp -> P to per-wave LDS (bf16) ->
// 2 ds_read_b128 A-frags -> 4 PV mfma. Online sum-of-exp (no max: logits ~N(0,1)).
// No __syncthreads anywhere (P buffer is wave-private).
// Output A fp32 in [b][c][p] layout (c = head*32+d).
// ---------------------------------------------------------------------------
__global__ __launch_bounds__(256) void attn_mfma(const __hip_bfloat16* __restrict__ Q,
                                                 const __hip_bfloat16* __restrict__ K,
                                                 const __hip_bfloat16* __restrict__ Vt,
                                                 float* __restrict__ A) {
  __shared__ unsigned short Plds[4][16 * 72];  // per-wave 16 x 64 bf16, stride 72
  const int t = threadIdx.x;
  const int wave = t >> 6, lane = t & 63;
  const int quad = lane >> 4, n16 = lane & 15;
  const int bh = blockIdx.y;
  const int i0w = blockIdx.x * 64 + wave * 16;  // 16 queries per wave
  const size_t hb = (size_t)bh * (HW * HD);

  // Q A-frag: A[m=n16][k=quad*8+j] -- 16B contiguous per lane, wave covers 1KB
  bf16x8 qf = *(const bf16x8*)((const short*)Q + hb + (size_t)(i0w + n16) * HD + quad * 8);
  f32x4 O0 = {0.f, 0.f, 0.f, 0.f};
  f32x4 O1 = {0.f, 0.f, 0.f, 0.f};
  const f32x4 zero = {0.f, 0.f, 0.f, 0.f};
  float l[4] = {0.f, 0.f, 0.f, 0.f};
  unsigned short* Pw = &Plds[wave][0];
  const int m_row = quad * 4;

  for (int jt = 0; jt < 16; ++jt) {
    const int j0 = jt * 64;
    f32x4 S[4];
#pragma unroll
    for (int kk = 0; kk < 4; ++kk) {
      bf16x8 kf = *(const bf16x8*)((const short*)K + hb + (size_t)(j0 + kk * 16 + n16) * HD + quad * 8);
      S[kk] = __builtin_amdgcn_mfma_f32_16x16x32_bf16(qf, kf, zero, 0, 0, 0);
    }
#pragma unroll
    for (int kk = 0; kk < 4; ++kk) {
#pragma unroll
      for (int r = 0; r < 4; ++r) {
        float e = __expf(S[kk][r]);
        l[r] += e;
        __hip_bfloat16 h = __float2bfloat16(e);
        Pw[(m_row + r) * 72 + kk * 16 + n16] = *(const unsigned short*)&h;
      }
    }
#pragma unroll
    for (int c = 0; c < 2; ++c) {
      bf16x8 pf = *(const bf16x8*)(Pw + n16 * 72 + c * 32 + quad * 8);
      bf16x8 v0 = *(const bf16x8*)((const short*)Vt + hb + (size_t)n16 * HW + j0 + c * 32 + quad * 8);
      bf16x8 v1 = *(const bf16x8*)((const short*)Vt + hb + (size_t)(16 + n16) * HW + j0 + c * 32 + quad * 8);
      O0 = __builtin_amdgcn_mfma_f32_16x16x32_bf16(pf, v0, O0, 0, 0, 0);
      O1 = __builtin_amdgcn_mfma_f32_16x16x32_bf16(pf, v1, O1, 0, 0, 0);
    }
  }
  // finish row sums: reduce across the 16 lanes of each quad
#pragma unroll
  for (int r = 0; r < 4; ++r) {
    l[r] += __shfl_xor(l[r], 1);
    l[r] += __shfl_xor(l[r], 2);
    l[r] += __shfl_xor(l[r], 4);
    l[r] += __shfl_xor(l[r], 8);
    l[r] = 1.f / l[r];
  }
  // O frags: row m=quad*4+r -> p = i0w+quad*4+r (contiguous across r => float4 store)
  float4 w0, w1;
  w0.x = O0[0] * l[0]; w0.y = O0[1] * l[1]; w0.z = O0[2] * l[2]; w0.w = O0[3] * l[3];
  w1.x = O1[0] * l[0]; w1.y = O1[1] * l[1]; w1.z = O1[2] * l[2]; w1.w = O1[3] * l[3];
  *(float4*)(A + hb + (size_t)n16 * HW + i0w + quad * 4) = w0;
  *(float4*)(A + hb + (size_t)(16 + n16) * HW + i0w + quad * 4) = w1;
}

// ---------------------------------------------------------------------------
// Kernel 3: proj = w_proj(256x256) @ A_b(256x1024) -> P [b][c][p]
// ---------------------------------------------------------------------------
__global__ __launch_bounds__(256) void proj_gemm(const float* __restrict__ Ain,
                                                 const float* __restrict__ w,
                                                 float* __restrict__ P) {
  __shared__ float Wt[64][68];
  __shared__ float Xt[64][68];
  const int t = threadIdx.x;
  const int o0 = blockIdx.x * 64;   // 0..3
  const int p0 = blockIdx.y * 64;   // 0..15
  const int b  = blockIdx.z;
  const int tx = t & 15, ty = t >> 4;
  float acc[4][4] = {};
  for (int c0 = 0; c0 < CCH; c0 += 64) {
#pragma unroll
    for (int k = 0; k < 4; ++k) {
      int fidx = t + k * 256;
      int r = fidx >> 4, c4 = fidx & 15;
      *(float4*)&Wt[r][c4 * 4] =
          *(const float4*)(w + (size_t)(o0 + r) * CCH + c0 + c4 * 4);
      *(float4*)&Xt[r][c4 * 4] =
          *(const float4*)(Ain + (size_t)b * (CCH * HW) + (size_t)(c0 + r) * HW + p0 + c4 * 4);
    }
    __syncthreads();
#pragma unroll
    for (int cc4 = 0; cc4 < 16; ++cc4) {
      float xs[4][4];
#pragma unroll
      for (int q = 0; q < 4; ++q) {
        float4 v = *(const float4*)&Xt[cc4 * 4 + q][tx * 4];
        xs[q][0] = v.x; xs[q][1] = v.y; xs[q][2] = v.z; xs[q][3] = v.w;
      }
#pragma unroll
      for (int i = 0; i < 4; ++i) {
        float4 wv = *(const float4*)&Wt[ty * 4 + i][cc4 * 4];
#pragma unroll
        for (int j = 0; j < 4; ++j)
          acc[i][j] += wv.x * xs[0][j] + wv.y * xs[1][j] + wv.z * xs[2][j] + wv.w * xs[3][j];
      }
    }
    __syncthreads();
  }
#pragma unroll
  for (int i = 0; i < 4; ++i) {
    int o = o0 + ty * 4 + i;
    float4 v = make_float4(acc[i][0], acc[i][1], acc[i][2], acc[i][3]);
    *(float4*)&P[(size_t)b * (CCH * HW) + (size_t)o * HW + p0 + tx * 4] = v;
  }
}

// ---------------------------------------------------------------------------
// Kernel 4: GroupNorm stats per (b,g): contiguous 32768-float segment of P
// ---------------------------------------------------------------------------
__global__ __launch_bounds__(256) void gn_stats(const float* __restrict__ P,
                                                float* __restrict__ stats) {
  __shared__ float r1[256], r2[256];
  const int t = threadIdx.x;
  const int bg = blockIdx.x;  // 0..127
  const float4* Pg = (const float4*)(P + (size_t)bg * 32768);
  float s1 = 0.f, s2 = 0.f;
  for (int idx = t; idx < 8192; idx += 256) {
    float4 v = Pg[idx];
    s1 += v.x + v.y + v.z + v.w;
    s2 += v.x * v.x + v.y * v.y + v.z * v.z + v.w * v.w;
  }
  r1[t] = s1; r2[t] = s2;
  __syncthreads();
  for (int off = 128; off > 0; off >>= 1) {
    if (t < off) { r1[t] += r1[t + off]; r2[t] += r2[t + off]; }
    __syncthreads();
  }
  if (t == 0) {
    float mean = r1[0] * (1.f / 32768.f);
    float var = r2[0] * (1.f / 32768.f) - mean * mean;
    stats[bg * 2] = mean;
    stats[bg * 2 + 1] = rsqrtf(var + 1e-5f);
  }
}

// ---------------------------------------------------------------------------
// Kernel 5: out = (P - mean)*inv*gamma + beta + x
// ---------------------------------------------------------------------------
__global__ __launch_bounds__(256) void gn_apply(const float* __restrict__ P,
                                                const float* __restrict__ x,
                                                const float* __restrict__ gamma,
                                                const float* __restrict__ beta,
                                                const float* __restrict__ stats,
                                                float* __restrict__ out) {
  int i4 = blockIdx.x * 256 + threadIdx.x;   // 1048576 float4s
  int c = (i4 >> 8) & 255;
  int bg = i4 >> 13;
  float mean = stats[bg * 2];
  float inv = stats[bg * 2 + 1];
  float ga = gamma[c] * inv;
  float be = beta[c] - mean * ga;
  float4 p = ((const float4*)P)[i4];
  float4 xr = ((const float4*)x)[i4];
  float4 o;
  o.x = p.x * ga + be + xr.x;
  o.y = p.y * ga + be + xr.y;
  o.z = p.z * ga + be + xr.z;
  o.w = p.w * ga + be + xr.w;
  ((float4*)out)[i4] = o;
}

// ---------------------------------------------------------------------------
extern "C" void kernel_launch(void* const* d_in, const int* in_sizes, int n_in,
                              void* d_out, int out_size, void* d_ws, size_t ws_size,
                              hipStream_t stream) {
  const float* x      = (const float*)d_in[0];
  const float* w_qkv  = (const float*)d_in[1];
  const float* w_proj = (const float*)d_in[2];
  const float* gamma  = (const float*)d_in[3];
  const float* beta   = (const float*)d_in[4];
  float* out = (float*)d_out;

  float* ws = (float*)d_ws;
  const size_t SZ = (size_t)BATCH * CCH * HW;  // 4,194,304 elements
  float* A = ws;                  // fp32 [b][c][p]
  float* P = A + SZ;              // fp32 [b][c][p]
  float* stats = P + SZ;          // 256 floats
  __hip_bfloat16* Qb  = (__hip_bfloat16*)(stats + 256);
  __hip_bfloat16* Kb  = Qb + SZ;
  __hip_bfloat16* Vtb = Kb + SZ;

  qkv_gemm<<<dim3(12, 16, BATCH), 256, 0, stream>>>(x, w_qkv, Qb, Kb, Vtb);
  attn_mfma<<<dim3(16, BATCH * NH), 256, 0, stream>>>(Qb, Kb, Vtb, A);
  proj_gemm<<<dim3(4, 16, BATCH), 256, 0, stream>>>(A, w_proj, P);
  gn_stats<<<128, 256, 0, stream>>>(P, stats);
  gn_apply<<<4096, 256, 0, stream>>>(P, x, gamma, beta, stats, out);
}

// Round 3
// 218.590 us; speedup vs baseline: 3.8599x; 2.0645x over previous
//
#include <hip/hip_runtime.h>
#include <hip/hip_bf16.h>
#include <math.h>

#define BATCH 16
#define CCH 256
#define HW 1024
#define NH 8
#define HD 32
#define SCALE 0.17677669529663687f  // 1/sqrt(32)

typedef __attribute__((ext_vector_type(8))) short bf16x8;  // 8 bf16 = 4 VGPRs
typedef __attribute__((ext_vector_type(4))) float f32x4;

__device__ __forceinline__ unsigned short bf16bits(float f) {
  __hip_bfloat16 h = __float2bfloat16(f);
  return *(unsigned short*)&h;
}

// async global->LDS, 16B per lane; lds dest must be wave-uniform base (+lane*16)
__device__ __forceinline__ void gload16(const void* g, void* l) {
  __builtin_amdgcn_global_load_lds(
      (const __attribute__((address_space(1))) unsigned int*)g,
      (__attribute__((address_space(3))) unsigned int*)l, 16, 0, 0);
}

// ---------------------------------------------------------------------------
// Convert weights fp32 -> bf16 (same layout, k contiguous)
// ---------------------------------------------------------------------------
__global__ __launch_bounds__(256) void cvt_w(const float* __restrict__ w,
                                             unsigned short* __restrict__ wb, int n4) {
  int i = blockIdx.x * 256 + threadIdx.x;
  if (i >= n4) return;
  float4 v = ((const float4*)w)[i];
  ushort4 o;
  o.x = bf16bits(v.x); o.y = bf16bits(v.y); o.z = bf16bits(v.z); o.w = bf16bits(v.w);
  ((ushort4*)wb)[i] = o;
}

// ---------------------------------------------------------------------------
// Transpose-convert x fp32 [b][c][p] -> xt bf16 [b][p][c]
// ---------------------------------------------------------------------------
__global__ __launch_bounds__(256) void cvt_x(const float* __restrict__ x,
                                             unsigned short* __restrict__ xt) {
  __shared__ unsigned short tile[64][72];  // [p_local][c_local], stride 72 (8B-aligned rows)
  const int t = threadIdx.x;
  const int p0 = blockIdx.x * 64;
  const int c0 = blockIdx.y * 64;
  const int b = blockIdx.z;
  const float* xb = x + (size_t)b * CCH * HW;
#pragma unroll
  for (int i = 0; i < 4; ++i) {
    int f = i * 256 + t;
    int c = f >> 4, p4 = f & 15;
    float4 v = *(const float4*)(xb + (size_t)(c0 + c) * HW + p0 + p4 * 4);
    tile[p4 * 4 + 0][c] = bf16bits(v.x);
    tile[p4 * 4 + 1][c] = bf16bits(v.y);
    tile[p4 * 4 + 2][c] = bf16bits(v.z);
    tile[p4 * 4 + 3][c] = bf16bits(v.w);
  }
  __syncthreads();
  unsigned short* xtb = xt + (size_t)b * HW * CCH;
#pragma unroll
  for (int i = 0; i < 4; ++i) {
    int f = i * 256 + t;
    int p = f >> 4, c4 = f & 15;
    ushort4 v = *(const ushort4*)&tile[p][c4 * 4];
    *(ushort4*)(xtb + (size_t)(p0 + p) * CCH + c0 + c4 * 4) = v;
  }
}

// ---------------------------------------------------------------------------
// Kernel 1: qkv MFMA GEMM. C[768,1024] = Wq[768,256] @ X[256,1024] per batch.
// 128x128 tile, BK=64, global_load_lds(16B), fragment-major LDS [kc][row]*bf16x8.
// Epilogue: Q (scaled) / K as [bh][p][d] bf16, V transposed [bh][d][p] bf16.
// ---------------------------------------------------------------------------
__global__ __launch_bounds__(256) void qkv_mfma(const unsigned short* __restrict__ Wb,
                                                const unsigned short* __restrict__ Xt,
                                                unsigned short* __restrict__ Qb,
                                                unsigned short* __restrict__ Kb,
                                                unsigned short* __restrict__ Vtb) {
  __shared__ unsigned short A_l[8 * 128 * 8];  // 16 KB
  __shared__ unsigned short B_l[8 * 128 * 8];  // 16 KB
  const int t = threadIdx.x;
  const int wave = t >> 6, lane = t & 63;
  const int quad = lane >> 4, n16 = lane & 15;
  const int o0 = blockIdx.x * 128;
  const int p0 = blockIdx.y * 128;
  const int b = blockIdx.z;
  const int wm = (wave >> 1) * 64, wn = (wave & 1) * 64;
  const unsigned short* Xb = Xt + (size_t)b * (HW * CCH);

  f32x4 acc[4][4] = {};
  for (int k0 = 0; k0 < CCH; k0 += 64) {
#pragma unroll
    for (int i = 0; i < 4; ++i) {
      int f = i * 256 + t;
      int kc = f >> 7, m = f & 127;
      int dst = (i * 256 + wave * 64) * 8;  // wave-uniform
      gload16(Wb + (size_t)(o0 + m) * CCH + k0 + kc * 8, &A_l[dst]);
      gload16(Xb + (size_t)(p0 + m) * CCH + k0 + kc * 8, &B_l[dst]);
    }
    __syncthreads();
#pragma unroll
    for (int ks = 0; ks < 2; ++ks) {
      bf16x8 af[4], bfr[4];
#pragma unroll
      for (int mi = 0; mi < 4; ++mi)
        af[mi] = *(const bf16x8*)&A_l[((ks * 4 + quad) * 128 + wm + mi * 16 + n16) * 8];
#pragma unroll
      for (int ni = 0; ni < 4; ++ni)
        bfr[ni] = *(const bf16x8*)&B_l[((ks * 4 + quad) * 128 + wn + ni * 16 + n16) * 8];
#pragma unroll
      for (int mi = 0; mi < 4; ++mi)
#pragma unroll
        for (int ni = 0; ni < 4; ++ni)
          acc[mi][ni] = __builtin_amdgcn_mfma_f32_16x16x32_bf16(af[mi], bfr[ni], acc[mi][ni], 0, 0, 0);
    }
    __syncthreads();
  }
  // epilogue: three = 0(Q)/1(K)/2(V), uniform per block (o0 is 128-aligned, thirds 256-aligned)
  const int three = o0 >> 8;
#pragma unroll
  for (int mi = 0; mi < 4; ++mi) {
    int o = o0 + wm + mi * 16 + quad * 4;  // rows o..o+3 via regs
    int head = (o >> 5) & 7;
    int d0 = o & 31;
    size_t bh_base = (size_t)(b * NH + head) * (HW * HD);
#pragma unroll
    for (int ni = 0; ni < 4; ++ni) {
      int p = p0 + wn + ni * 16 + n16;
      if (three == 0) {
        ushort4 st;
        st.x = bf16bits(acc[mi][ni][0] * SCALE);
        st.y = bf16bits(acc[mi][ni][1] * SCALE);
        st.z = bf16bits(acc[mi][ni][2] * SCALE);
        st.w = bf16bits(acc[mi][ni][3] * SCALE);
        *(ushort4*)&Qb[bh_base + (size_t)p * HD + d0] = st;
      } else if (three == 1) {
        ushort4 st;
        st.x = bf16bits(acc[mi][ni][0]);
        st.y = bf16bits(acc[mi][ni][1]);
        st.z = bf16bits(acc[mi][ni][2]);
        st.w = bf16bits(acc[mi][ni][3]);
        *(ushort4*)&Kb[bh_base + (size_t)p * HD + d0] = st;
      } else {
#pragma unroll
        for (int r = 0; r < 4; ++r)
          Vtb[bh_base + (size_t)(d0 + r) * HW + p] = bf16bits(acc[mi][ni][r]);
      }
    }
  }
}

// ---------------------------------------------------------------------------
// Kernel 2: MFMA flash attention (unchanged core). Output now bf16 Ab[b][p][c].
// ---------------------------------------------------------------------------
__global__ __launch_bounds__(256) void attn_mfma(const unsigned short* __restrict__ Q,
                                                 const unsigned short* __restrict__ K,
                                                 const unsigned short* __restrict__ Vt,
                                                 unsigned short* __restrict__ Ab) {
  __shared__ unsigned short Plds[4][16 * 72];  // per-wave 16 x 64 bf16, stride 72
  const int t = threadIdx.x;
  const int wave = t >> 6, lane = t & 63;
  const int quad = lane >> 4, n16 = lane & 15;
  const int bh = blockIdx.y;
  const int i0w = blockIdx.x * 64 + wave * 16;  // 16 queries per wave
  const size_t hb = (size_t)bh * (HW * HD);

  bf16x8 qf = *(const bf16x8*)((const short*)Q + hb + (size_t)(i0w + n16) * HD + quad * 8);
  f32x4 O0 = {0.f, 0.f, 0.f, 0.f};
  f32x4 O1 = {0.f, 0.f, 0.f, 0.f};
  const f32x4 zero = {0.f, 0.f, 0.f, 0.f};
  float l[4] = {0.f, 0.f, 0.f, 0.f};
  unsigned short* Pw = &Plds[wave][0];
  const int m_row = quad * 4;

  for (int jt = 0; jt < 16; ++jt) {
    const int j0 = jt * 64;
    f32x4 S[4];
#pragma unroll
    for (int kk = 0; kk < 4; ++kk) {
      bf16x8 kf = *(const bf16x8*)((const short*)K + hb + (size_t)(j0 + kk * 16 + n16) * HD + quad * 8);
      S[kk] = __builtin_amdgcn_mfma_f32_16x16x32_bf16(qf, kf, zero, 0, 0, 0);
    }
#pragma unroll
    for (int kk = 0; kk < 4; ++kk) {
#pragma unroll
      for (int r = 0; r < 4; ++r) {
        float e = __expf(S[kk][r]);
        l[r] += e;
        Pw[(m_row + r) * 72 + kk * 16 + n16] = bf16bits(e);
      }
    }
#pragma unroll
    for (int c = 0; c < 2; ++c) {
      bf16x8 pf = *(const bf16x8*)(Pw + n16 * 72 + c * 32 + quad * 8);
      bf16x8 v0 = *(const bf16x8*)((const short*)Vt + hb + (size_t)n16 * HW + j0 + c * 32 + quad * 8);
      bf16x8 v1 = *(const bf16x8*)((const short*)Vt + hb + (size_t)(16 + n16) * HW + j0 + c * 32 + quad * 8);
      O0 = __builtin_amdgcn_mfma_f32_16x16x32_bf16(pf, v0, O0, 0, 0, 0);
      O1 = __builtin_amdgcn_mfma_f32_16x16x32_bf16(pf, v1, O1, 0, 0, 0);
    }
  }
#pragma unroll
  for (int r = 0; r < 4; ++r) {
    l[r] += __shfl_xor(l[r], 1);
    l[r] += __shfl_xor(l[r], 2);
    l[r] += __shfl_xor(l[r], 4);
    l[r] += __shfl_xor(l[r], 8);
    l[r] = 1.f / l[r];
  }
  // write Ab[b][p][c], c = head*32 + (n16 | 16+n16)
  const int bb = bh >> 3, head = bh & 7;
  unsigned short* dst = Ab + (size_t)bb * (HW * CCH) + head * 32;
#pragma unroll
  for (int r = 0; r < 4; ++r) {
    int p = i0w + quad * 4 + r;
    dst[(size_t)p * CCH + n16] = bf16bits(O0[r] * l[r]);
    dst[(size_t)p * CCH + 16 + n16] = bf16bits(O1[r] * l[r]);
  }
}

// ---------------------------------------------------------------------------
// Kernel 3: proj MFMA GEMM. P[256,1024] = Wp[256,256] @ A[256,1024] per batch.
// Output P fp32 [b][c][p] for GN.
// ---------------------------------------------------------------------------
__global__ __launch_bounds__(256) void proj_mfma(const unsigned short* __restrict__ Wb,
                                                 const unsigned short* __restrict__ At,
                                                 float* __restrict__ P) {
  __shared__ unsigned short A_l[8 * 128 * 8];
  __shared__ unsigned short B_l[8 * 128 * 8];
  const int t = threadIdx.x;
  const int wave = t >> 6, lane = t & 63;
  const int quad = lane >> 4, n16 = lane & 15;
  const int o0 = blockIdx.x * 128;
  const int p0 = blockIdx.y * 128;
  const int b = blockIdx.z;
  const int wm = (wave >> 1) * 64, wn = (wave & 1) * 64;
  const unsigned short* Ax = At + (size_t)b * (HW * CCH);

  f32x4 acc[4][4] = {};
  for (int k0 = 0; k0 < CCH; k0 += 64) {
#pragma unroll
    for (int i = 0; i < 4; ++i) {
      int f = i * 256 + t;
      int kc = f >> 7, m = f & 127;
      int dst = (i * 256 + wave * 64) * 8;
      gload16(Wb + (size_t)(o0 + m) * CCH + k0 + kc * 8, &A_l[dst]);
      gload16(Ax + (size_t)(p0 + m) * CCH + k0 + kc * 8, &B_l[dst]);
    }
    __syncthreads();
#pragma unroll
    for (int ks = 0; ks < 2; ++ks) {
      bf16x8 af[4], bfr[4];
#pragma unroll
      for (int mi = 0; mi < 4; ++mi)
        af[mi] = *(const bf16x8*)&A_l[((ks * 4 + quad) * 128 + wm + mi * 16 + n16) * 8];
#pragma unroll
      for (int ni = 0; ni < 4; ++ni)
        bfr[ni] = *(const bf16x8*)&B_l[((ks * 4 + quad) * 128 + wn + ni * 16 + n16) * 8];
#pragma unroll
      for (int mi = 0; mi < 4; ++mi)
#pragma unroll
        for (int ni = 0; ni < 4; ++ni)
          acc[mi][ni] = __builtin_amdgcn_mfma_f32_16x16x32_bf16(af[mi], bfr[ni], acc[mi][ni], 0, 0, 0);
    }
    __syncthreads();
  }
#pragma unroll
  for (int mi = 0; mi < 4; ++mi) {
    int o = o0 + wm + mi * 16 + quad * 4;
#pragma unroll
    for (int ni = 0; ni < 4; ++ni) {
      int p = p0 + wn + ni * 16 + n16;
#pragma unroll
      for (int r = 0; r < 4; ++r)
        P[(size_t)b * (CCH * HW) + (size_t)(o + r) * HW + p] = acc[mi][ni][r];
    }
  }
}

// ---------------------------------------------------------------------------
// Kernel 4: GroupNorm stats per (b,g)
// ---------------------------------------------------------------------------
__global__ __launch_bounds__(256) void gn_stats(const float* __restrict__ P,
                                                float* __restrict__ stats) {
  __shared__ float r1[256], r2[256];
  const int t = threadIdx.x;
  const int bg = blockIdx.x;  // 0..127
  const float4* Pg = (const float4*)(P + (size_t)bg * 32768);
  float s1 = 0.f, s2 = 0.f;
  for (int idx = t; idx < 8192; idx += 256) {
    float4 v = Pg[idx];
    s1 += v.x + v.y + v.z + v.w;
    s2 += v.x * v.x + v.y * v.y + v.z * v.z + v.w * v.w;
  }
  r1[t] = s1; r2[t] = s2;
  __syncthreads();
  for (int off = 128; off > 0; off >>= 1) {
    if (t < off) { r1[t] += r1[t + off]; r2[t] += r2[t + off]; }
    __syncthreads();
  }
  if (t == 0) {
    float mean = r1[0] * (1.f / 32768.f);
    float var = r2[0] * (1.f / 32768.f) - mean * mean;
    stats[bg * 2] = mean;
    stats[bg * 2 + 1] = rsqrtf(var + 1e-5f);
  }
}

// ---------------------------------------------------------------------------
// Kernel 5: out = (P - mean)*inv*gamma + beta + x
// ---------------------------------------------------------------------------
__global__ __launch_bounds__(256) void gn_apply(const float* __restrict__ P,
                                                const float* __restrict__ x,
                                                const float* __restrict__ gamma,
                                                const float* __restrict__ beta,
                                                const float* __restrict__ stats,
                                                float* __restrict__ out) {
  int i4 = blockIdx.x * 256 + threadIdx.x;   // 1048576 float4s
  int c = (i4 >> 8) & 255;
  int bg = i4 >> 13;
  float mean = stats[bg * 2];
  float inv = stats[bg * 2 + 1];
  float ga = gamma[c] * inv;
  float be = beta[c] - mean * ga;
  float4 p = ((const float4*)P)[i4];
  float4 xr = ((const float4*)x)[i4];
  float4 o;
  o.x = p.x * ga + be + xr.x;
  o.y = p.y * ga + be + xr.y;
  o.z = p.z * ga + be + xr.z;
  o.w = p.w * ga + be + xr.w;
  ((float4*)out)[i4] = o;
}

// ---------------------------------------------------------------------------
extern "C" void kernel_launch(void* const* d_in, const int* in_sizes, int n_in,
                              void* d_out, int out_size, void* d_ws, size_t ws_size,
                              hipStream_t stream) {
  const float* x      = (const float*)d_in[0];
  const float* w_qkv  = (const float*)d_in[1];
  const float* w_proj = (const float*)d_in[2];
  const float* gamma  = (const float*)d_in[3];
  const float* beta   = (const float*)d_in[4];
  float* out = (float*)d_out;

  const size_t SZ = (size_t)BATCH * CCH * HW;  // 4,194,304 elements
  float* P = (float*)d_ws;                     // fp32 [b][c][p]
  float* stats = P + SZ;                       // 256 floats
  unsigned short* Qb  = (unsigned short*)(stats + 256);
  unsigned short* Kb  = Qb + SZ;
  unsigned short* Vtb = Kb + SZ;
  unsigned short* Ab  = Vtb + SZ;              // bf16 [b][p][c]
  unsigned short* Xtb = Ab + SZ;               // bf16 [b][p][c]
  unsigned short* Wqb = Xtb + SZ;              // bf16 [768][256]
  unsigned short* Wpb = Wqb + (3 * CCH * CCH); // bf16 [256][256]

  cvt_w<<<192, 256, 0, stream>>>(w_qkv, Wqb, 3 * CCH * CCH / 4);
  cvt_w<<<64, 256, 0, stream>>>(w_proj, Wpb, CCH * CCH / 4);
  cvt_x<<<dim3(16, 4, BATCH), 256, 0, stream>>>(x, Xtb);
  qkv_mfma<<<dim3(6, 8, BATCH), 256, 0, stream>>>(Wqb, Xtb, Qb, Kb, Vtb);
  attn_mfma<<<dim3(16, BATCH * NH), 256, 0, stream>>>(Qb, Kb, Vtb, Ab);
  proj_mfma<<<dim3(2, 8, BATCH), 256, 0, stream>>>(Wpb, Ab, P);
  gn_stats<<<128, 256, 0, stream>>>(P, stats);
  gn_apply<<<4096, 256, 0, stream>>>(P, x, gamma, beta, stats, out);
}